// Round 11
// baseline (357.857 us; speedup 1.0000x reference)
//
#include <hip/hip_runtime.h>

// B=8, N=4096, Din=128, Dout=256. TT=16 tokens/block -> M = 3*16 = 48 rows.
// bf16 2-way split (hi/mid) + 3 product-class MFMAs = ~24-bit GEMMs.
// R11: MEASUREMENT ROUND. R10 post-mortem: per-wave issue ~5K cy vs ~53K cy
// resident; serialized-load arithmetic explains <half the wait. Three rounds
// of hypothesis-driven structure changes each moved counters but not the wall
// proportionally. Per methodology: ablate empirically before optimizing more.
//   - main kernel: BIT-IDENTICAL to R10 (124us, absmax 0.5) -> score is safe.
//   - probe_nomfma  (P1): phaseA + ALL global loads + LDS + barrier, no MFMA,
//     no out-stores; loads kept live via integer folds (anti-DCE, rule 17).
//   - probe_mfmaonly(P2): constant LDS init + barrier + all ds_reads + all 96
//     MFMAs (same dep chains) + VN epilogue math; ZERO global loads.
// Readout: dur_us_total - 280.7 = t1 + t2; slowest probe also appears in the
// per-dispatch table. Decision rule (pre-committed):
//   t1 >> t2  -> load-latency wall -> R12: TT=32 (halve per-token weight loads)
//   t2 >> t1  -> MFMA/LDS-chain wall -> R12: per-class accs + LDS swizzle
//   t1 ~= t2  -> poor phase overlap -> R12: interleave G1/G2 per-ks
#define TT 16
#define NBLK 2048
#define LDA 136   // aT row stride (bf16): 128 + 8 pad

typedef short s16x8 __attribute__((ext_vector_type(8)));
typedef float f32x4 __attribute__((ext_vector_type(4)));

#define SCHED_FENCE() __builtin_amdgcn_sched_barrier(0)

__device__ __forceinline__ unsigned short f2bf(float f) {
  union { float f; unsigned u; } v; v.f = f;
  unsigned r = v.u + 0x7FFFu + ((v.u >> 16) & 1u);   // RNE; inputs finite
  return (unsigned short)(r >> 16);
}
__device__ __forceinline__ float bf2f(unsigned short h) {
  union { unsigned u; float f; } v; v.u = ((unsigned)h) << 16;
  return v.f;
}
__device__ __forceinline__ void split2(float x, unsigned short& h, unsigned short& m) {
  h = f2bf(x);
  m = f2bf(x - bf2f(h));   // exact subtraction
}

// prep1: M3 = A+B+C -> fp32 buffer (for prep2) + bf16x2 planes (for GEMM1)
__global__ __launch_bounds__(256) void prep1_kernel(
    const float* __restrict__ A, const float* __restrict__ Bm,
    const float* __restrict__ C,
    float* __restrict__ M3f,
    unsigned short* __restrict__ M3h, unsigned short* __restrict__ M3m) {
  int tid = blockIdx.x * 256 + threadIdx.x;   // 0..32767
  float s = A[tid] + Bm[tid] + C[tid];
  M3f[tid] = s;
  unsigned short h, m;
  split2(s, h, m);
  M3h[tid] = h; M3m[tid] = m;
}

// prep2: WM3[o][e] = sum_c W[o][c] * M3f[c][e], split to bf16x2 planes.
// (known ~13us, 1 block/CU latency-bound; left unchanged this round so the
// probe arithmetic dur_total - 280.7 = t1 + t2 stays clean)
__global__ __launch_bounds__(128) void prep2_kernel(
    const float* __restrict__ W, const float* __restrict__ M3f,
    unsigned short* __restrict__ WMh, unsigned short* __restrict__ WMm) {
  __shared__ float wrow[256];
  const int o = blockIdx.x;
  const int e = threadIdx.x;
  wrow[e]       = W[o * 256 + e];
  wrow[e + 128] = W[o * 256 + 128 + e];
  __syncthreads();
  float dot = 0.f;
  #pragma unroll 8
  for (int c = 0; c < 256; ++c) dot += wrow[c] * M3f[c * 128 + e];
  unsigned short h, m;
  split2(dot, h, m);
  WMh[o * 128 + e] = h; WMm[o * 128 + e] = m;
}

// rolling-prefetch load macros (all indices compile-time constant).
#define B1LOAD(ks) { \
  b1h[ks][0] = *(const s16x8*)(M3h + fB + (ks) * 32); \
  b1m[ks][0] = *(const s16x8*)(M3m + fB + (ks) * 32); \
  b1h[ks][1] = *(const s16x8*)(M3h + fB + 2048 + (ks) * 32); \
  b1m[ks][1] = *(const s16x8*)(M3m + fB + 2048 + (ks) * 32); }

#define WMLOAD(ks) { \
  wmh[ks][0] = *(const s16x8*)(WMh + fB + (ks) * 32); \
  wmm[ks][0] = *(const s16x8*)(WMm + fB + (ks) * 32); \
  wmh[ks][1] = *(const s16x8*)(WMh + fB + 2048 + (ks) * 32); \
  wmm[ks][1] = *(const s16x8*)(WMm + fB + 2048 + (ks) * 32); }

#define G1STEP(ks) { \
  const int e0 = (ks) * 32 + quad * 8; \
  _Pragma("unroll") \
  for (int mt = 0; mt < 3; ++mt) { \
    s16x8 ah = *(const s16x8*)(aTh + (mt * 16 + nl) * LDA + e0); \
    s16x8 am = *(const s16x8*)(aTm + (mt * 16 + nl) * LDA + e0); \
    _Pragma("unroll") \
    for (int nt = 0; nt < 2; ++nt) { \
      f32x4 a = acc1[mt][nt]; \
      a = __builtin_amdgcn_mfma_f32_16x16x32_bf16(ah, b1h[ks][nt], a, 0, 0, 0); \
      a = __builtin_amdgcn_mfma_f32_16x16x32_bf16(ah, b1m[ks][nt], a, 0, 0, 0); \
      a = __builtin_amdgcn_mfma_f32_16x16x32_bf16(am, b1h[ks][nt], a, 0, 0, 0); \
      acc1[mt][nt] = a; \
    } \
  } }

#define G2STEP(ks) { \
  const int e0 = (ks) * 32 + quad * 8; \
  _Pragma("unroll") \
  for (int mt = 0; mt < 3; ++mt) { \
    s16x8 ah = *(const s16x8*)(aTh + (mt * 16 + nl) * LDA + e0); \
    s16x8 am = *(const s16x8*)(aTm + (mt * 16 + nl) * LDA + e0); \
    _Pragma("unroll") \
    for (int nt = 0; nt < 2; ++nt) { \
      f32x4 a = acc2[mt][nt]; \
      a = __builtin_amdgcn_mfma_f32_16x16x32_bf16(ah, wmh[ks][nt], a, 0, 0, 0); \
      a = __builtin_amdgcn_mfma_f32_16x16x32_bf16(ah, wmm[ks][nt], a, 0, 0, 0); \
      a = __builtin_amdgcn_mfma_f32_16x16x32_bf16(am, wmh[ks][nt], a, 0, 0, 0); \
      acc2[mt][nt] = a; \
    } \
  } }

// ======================= MAIN KERNEL (bit-identical to R10) =================
__global__ __launch_bounds__(512, 4) void affine_vnrelu_mfma(
    const float* __restrict__ X, const float* __restrict__ J,
    const unsigned short* __restrict__ M3h, const unsigned short* __restrict__ M3m,
    const unsigned short* __restrict__ WMh, const unsigned short* __restrict__ WMm,
    float* __restrict__ out) {
  __shared__ unsigned short smem[2 * 48 * LDA];   // aT hi/mid, 26112 B
  unsigned short* aTh = smem;
  unsigned short* aTm = smem + 48 * LDA;

  const int tid = threadIdx.x;
  const int lane = tid & 63;
  const int w = tid >> 6;          // wave 0..7 -> f slice [32w, 32w+32)
  const int quad = lane >> 4;
  const int nl = lane & 15;
  const long g0 = (long)blockIdx.x * TT;
  const int b = (int)(g0 >> 12);   // N = 4096
  const int n0 = (int)(g0 & 4095);
  const int f0 = w * 32;
  const int fB = (f0 + nl) * 128 + quad * 8;
  const f32x4 zz = {0.f, 0.f, 0.f, 0.f};

  s16x8 b1h[4][2], b1m[4][2];
  s16x8 wmh[4][2], wmm[4][2];
  B1LOAD(0);
  SCHED_FENCE();

  // ---------------- Phase A (vectorized): 1 thread = 4 channels of 1 token --
  {
    int t = tid >> 5;
    int dch0 = (tid & 31) * 4;
    const float* Xp = X + ((g0 + t) * 128 + dch0) * 3;
    const float* Jp = J + ((g0 + t) * 128 + dch0) * 6;
    float xf[12], jf[24];
    #pragma unroll
    for (int q = 0; q < 3; ++q) *(float4*)(xf + 4 * q) = ((const float4*)Xp)[q];
    #pragma unroll
    for (int q = 0; q < 6; ++q) *(float4*)(jf + 4 * q) = ((const float4*)Jp)[q];

    unsigned short hs[3][4], ms[3][4];
    #pragma unroll
    for (int e = 0; e < 4; ++e) {
      float x0 = xf[3 * e], x1 = xf[3 * e + 1], x2 = xf[3 * e + 2];
      float j0 = jf[6 * e],     j1 = jf[6 * e + 1], j2 = jf[6 * e + 2];
      float j3 = jf[6 * e + 3], j4 = jf[6 * e + 4], j5 = jf[6 * e + 5];
      float c00 = j0, c01 = j2, c02 = j4;
      float a20 = j1, a21 = j3, a22 = j5;
      float nsq1 = c00 * c00 + c01 * c01 + c02 * c02;
      float inv1 = __builtin_amdgcn_rsqf(fmaxf(nsq1, 1e-24f));
      float b10 = c00 * inv1, b11 = c01 * inv1, b12 = c02 * inv1;
      float pr = b10 * a20 + b11 * a21 + b12 * a22;
      float u0 = a20 - pr * b10, u1 = a21 - pr * b11, u2 = a22 - pr * b12;
      float nsq2 = u0 * u0 + u1 * u1 + u2 * u2;
      float inv2 = __builtin_amdgcn_rsqf(fmaxf(nsq2, 1e-24f));
      float b20 = u0 * inv2, b21 = u1 * inv2, b22 = u2 * inv2;
      float b30 = b11 * b22 - b12 * b21;
      float b31 = b12 * b20 - b10 * b22;
      float b32 = b10 * b21 - b11 * b20;
      split2(b10 * x0 + b11 * x1 + b12 * x2, hs[0][e], ms[0][e]);
      split2(b20 * x0 + b21 * x1 + b22 * x2, hs[1][e], ms[1][e]);
      split2(b30 * x0 + b31 * x1 + b32 * x2, hs[2][e], ms[2][e]);
    }
    #pragma unroll
    for (int i = 0; i < 3; ++i) {
      short4 vh, vm;
      vh.x = hs[i][0]; vh.y = hs[i][1]; vh.z = hs[i][2]; vh.w = hs[i][3];
      vm.x = ms[i][0]; vm.y = ms[i][1]; vm.z = ms[i][2]; vm.w = ms[i][3];
      int ro = (i * 16 + t) * LDA + dch0;
      *(short4*)(aTh + ro) = vh;
      *(short4*)(aTm + ro) = vm;
    }
  }
  __syncthreads();   // the single barrier: aT ready

  f32x4 acc1[3][2];
  #pragma unroll
  for (int mt = 0; mt < 3; ++mt)
    #pragma unroll
    for (int nt = 0; nt < 2; ++nt) acc1[mt][nt] = zz;

  B1LOAD(1);
  SCHED_FENCE();
  G1STEP(0);
  B1LOAD(2);
  SCHED_FENCE();
  G1STEP(1);
  B1LOAD(3);
  SCHED_FENCE();
  G1STEP(2);
  WMLOAD(0); WMLOAD(1);
  SCHED_FENCE();
  G1STEP(3);

  f32x4 acc2[3][2];
  #pragma unroll
  for (int mt = 0; mt < 3; ++mt)
    #pragma unroll
    for (int nt = 0; nt < 2; ++nt) acc2[mt][nt] = zz;

  G2STEP(0);
  WMLOAD(2);
  SCHED_FENCE();
  G2STEP(1);
  WMLOAD(3);
  SCHED_FENCE();
  G2STEP(2);
  G2STEP(3);

  #pragma unroll
  for (int nt = 0; nt < 2; ++nt) {
    int f = f0 + nt * 16 + nl;
    float* ob = out + ((long)(b * 256 + f) * 3) * 4096 + n0 + quad * 4;
    float o[3][4];
    #pragma unroll
    for (int r = 0; r < 4; ++r) {
      float x0 = acc1[0][nt][r], x1 = acc1[1][nt][r], x2 = acc1[2][nt][r];
      float d0 = acc2[0][nt][r], d1 = acc2[1][nt][r], d2 = acc2[2][nt][r];
      float dot = x0 * d0 + x1 * d1 + x2 * d2;
      float dn = d0 * d0 + d1 * d1 + d2 * d2;
      float s = (dot < 0.0f) ? (0.8f * dot * __builtin_amdgcn_rcpf(dn + 1e-6f))
                             : 0.0f;
      o[0][r] = x0 - s * d0;
      o[1][r] = x1 - s * d1;
      o[2][r] = x2 - s * d2;
    }
    #pragma unroll
    for (int i = 0; i < 3; ++i)
      *(float4*)(ob + ((long)i * 4096)) = make_float4(o[i][0], o[i][1], o[i][2], o[i][3]);
  }
}

// ======================= PROBE 1: everything except MFMA ====================
// phaseA + ALL global loads (pinned schedule identical) + LDS + barrier.
// Loads folded into an integer sink (anti-DCE). No MFMA, no 100MB store.
#define FOLD8(v) { fs += (unsigned)(unsigned short)(v)[0] + (unsigned)(unsigned short)(v)[7]; }

__global__ __launch_bounds__(512, 4) void probe_nomfma(
    const float* __restrict__ X, const float* __restrict__ J,
    const unsigned short* __restrict__ M3h, const unsigned short* __restrict__ M3m,
    const unsigned short* __restrict__ WMh, const unsigned short* __restrict__ WMm,
    unsigned* __restrict__ sink) {
  __shared__ unsigned short smem[2 * 48 * LDA];
  unsigned short* aTh = smem;
  unsigned short* aTm = smem + 48 * LDA;

  const int tid = threadIdx.x;
  const int lane = tid & 63;
  const int w = tid >> 6;
  const int quad = lane >> 4;
  const int nl = lane & 15;
  const long g0 = (long)blockIdx.x * TT;
  const int f0 = w * 32;
  const int fB = (f0 + nl) * 128 + quad * 8;

  unsigned fs = 0;
  s16x8 b1h[4][2], b1m[4][2];
  s16x8 wmh[4][2], wmm[4][2];
  B1LOAD(0);
  SCHED_FENCE();

  {  // phase A identical to main
    int t = tid >> 5;
    int dch0 = (tid & 31) * 4;
    const float* Xp = X + ((g0 + t) * 128 + dch0) * 3;
    const float* Jp = J + ((g0 + t) * 128 + dch0) * 6;
    float xf[12], jf[24];
    #pragma unroll
    for (int q = 0; q < 3; ++q) *(float4*)(xf + 4 * q) = ((const float4*)Xp)[q];
    #pragma unroll
    for (int q = 0; q < 6; ++q) *(float4*)(jf + 4 * q) = ((const float4*)Jp)[q];
    unsigned short hs[3][4], ms[3][4];
    #pragma unroll
    for (int e = 0; e < 4; ++e) {
      float x0 = xf[3 * e], x1 = xf[3 * e + 1], x2 = xf[3 * e + 2];
      float j0 = jf[6 * e],     j1 = jf[6 * e + 1], j2 = jf[6 * e + 2];
      float j3 = jf[6 * e + 3], j4 = jf[6 * e + 4], j5 = jf[6 * e + 5];
      float c00 = j0, c01 = j2, c02 = j4;
      float a20 = j1, a21 = j3, a22 = j5;
      float nsq1 = c00 * c00 + c01 * c01 + c02 * c02;
      float inv1 = __builtin_amdgcn_rsqf(fmaxf(nsq1, 1e-24f));
      float b10 = c00 * inv1, b11 = c01 * inv1, b12 = c02 * inv1;
      float pr = b10 * a20 + b11 * a21 + b12 * a22;
      float u0 = a20 - pr * b10, u1 = a21 - pr * b11, u2 = a22 - pr * b12;
      float nsq2 = u0 * u0 + u1 * u1 + u2 * u2;
      float inv2 = __builtin_amdgcn_rsqf(fmaxf(nsq2, 1e-24f));
      float b20 = u0 * inv2, b21 = u1 * inv2, b22 = u2 * inv2;
      float b30 = b11 * b22 - b12 * b21;
      float b31 = b12 * b20 - b10 * b22;
      float b32 = b10 * b21 - b11 * b20;
      split2(b10 * x0 + b11 * x1 + b12 * x2, hs[0][e], ms[0][e]);
      split2(b20 * x0 + b21 * x1 + b22 * x2, hs[1][e], ms[1][e]);
      split2(b30 * x0 + b31 * x1 + b32 * x2, hs[2][e], ms[2][e]);
    }
    #pragma unroll
    for (int i = 0; i < 3; ++i) {
      short4 vh, vm;
      vh.x = hs[i][0]; vh.y = hs[i][1]; vh.z = hs[i][2]; vh.w = hs[i][3];
      vm.x = ms[i][0]; vm.y = ms[i][1]; vm.z = ms[i][2]; vm.w = ms[i][3];
      int ro = (i * 16 + t) * LDA + dch0;
      *(short4*)(aTh + ro) = vh;
      *(short4*)(aTm + ro) = vm;
    }
  }
  __syncthreads();

  // GEMM1-shaped: same loads + same LDS reads, folds instead of MFMAs
  #define P1STEP(ks) { \
    const int e0 = (ks) * 32 + quad * 8; \
    _Pragma("unroll") \
    for (int mt = 0; mt < 3; ++mt) { \
      s16x8 ah = *(const s16x8*)(aTh + (mt * 16 + nl) * LDA + e0); \
      s16x8 am = *(const s16x8*)(aTm + (mt * 16 + nl) * LDA + e0); \
      FOLD8(ah); FOLD8(am); \
    } }

  B1LOAD(1);
  SCHED_FENCE();
  P1STEP(0); FOLD8(b1h[0][0]); FOLD8(b1h[0][1]); FOLD8(b1m[0][0]); FOLD8(b1m[0][1]);
  B1LOAD(2);
  SCHED_FENCE();
  P1STEP(1); FOLD8(b1h[1][0]); FOLD8(b1h[1][1]); FOLD8(b1m[1][0]); FOLD8(b1m[1][1]);
  B1LOAD(3);
  SCHED_FENCE();
  P1STEP(2); FOLD8(b1h[2][0]); FOLD8(b1h[2][1]); FOLD8(b1m[2][0]); FOLD8(b1m[2][1]);
  WMLOAD(0); WMLOAD(1);
  SCHED_FENCE();
  P1STEP(3); FOLD8(b1h[3][0]); FOLD8(b1h[3][1]); FOLD8(b1m[3][0]); FOLD8(b1m[3][1]);

  // GEMM2-shaped
  P1STEP(0); FOLD8(wmh[0][0]); FOLD8(wmh[0][1]); FOLD8(wmm[0][0]); FOLD8(wmm[0][1]);
  WMLOAD(2);
  SCHED_FENCE();
  P1STEP(1); FOLD8(wmh[1][0]); FOLD8(wmh[1][1]); FOLD8(wmm[1][0]); FOLD8(wmm[1][1]);
  WMLOAD(3);
  SCHED_FENCE();
  P1STEP(2); FOLD8(wmh[2][0]); FOLD8(wmh[2][1]); FOLD8(wmm[2][0]); FOLD8(wmm[2][1]);
  P1STEP(3); FOLD8(wmh[3][0]); FOLD8(wmh[3][1]); FOLD8(wmm[3][0]); FOLD8(wmm[3][1]);

  sink[blockIdx.x * 512 + tid] = fs;   // 4 MB, anti-DCE
}

// ======================= PROBE 2: MFMA+LDS structure only ===================
// Constant LDS init (no X/J loads, no GS), barrier, all 48 ds_reads + all 96
// MFMAs with identical dependency chains, weights = constant registers
// (zero global loads), VN epilogue math; one 4B sink write per thread.
__global__ __launch_bounds__(512, 4) void probe_mfmaonly(
    unsigned* __restrict__ sink) {
  __shared__ unsigned short smem[2 * 48 * LDA];
  unsigned short* aTh = smem;
  unsigned short* aTm = smem + 48 * LDA;

  const int tid = threadIdx.x;
  const int lane = tid & 63;
  const int quad = lane >> 4;
  const int nl = lane & 15;
  const f32x4 zz = {0.f, 0.f, 0.f, 0.f};

  {  // constant-data LDS init, same addresses as main's phase A
    int t = tid >> 5;
    int dch0 = (tid & 31) * 4;
    short4 vv; vv.x = 0x3f80; vv.y = 0x3f00; vv.z = 0xbf80; vv.w = 0x3e80;
    #pragma unroll
    for (int i = 0; i < 3; ++i) {
      int ro = (i * 16 + t) * LDA + dch0;
      *(short4*)(aTh + ro) = vv;
      *(short4*)(aTm + ro) = vv;
    }
  }
  __syncthreads();

  const s16x8 cb = {0x3f80, 0x3f00, (short)0xbf80, 0x3e80,
                    0x3f80, 0x3f00, (short)0xbf80, 0x3e80};

  f32x4 acc1[3][2], acc2[3][2];
  #pragma unroll
  for (int mt = 0; mt < 3; ++mt)
    #pragma unroll
    for (int nt = 0; nt < 2; ++nt) { acc1[mt][nt] = zz; acc2[mt][nt] = zz; }

  #define P2STEP(ks, acc) { \
    const int e0 = (ks) * 32 + quad * 8; \
    _Pragma("unroll") \
    for (int mt = 0; mt < 3; ++mt) { \
      s16x8 ah = *(const s16x8*)(aTh + (mt * 16 + nl) * LDA + e0); \
      s16x8 am = *(const s16x8*)(aTm + (mt * 16 + nl) * LDA + e0); \
      _Pragma("unroll") \
      for (int nt = 0; nt < 2; ++nt) { \
        f32x4 a = acc[mt][nt]; \
        a = __builtin_amdgcn_mfma_f32_16x16x32_bf16(ah, cb, a, 0, 0, 0); \
        a = __builtin_amdgcn_mfma_f32_16x16x32_bf16(ah, cb, a, 0, 0, 0); \
        a = __builtin_amdgcn_mfma_f32_16x16x32_bf16(am, cb, a, 0, 0, 0); \
        acc[mt][nt] = a; \
      } \
    } }

  P2STEP(0, acc1);
  P2STEP(1, acc1);
  P2STEP(2, acc1);
  P2STEP(3, acc1);
  P2STEP(0, acc2);
  P2STEP(1, acc2);
  P2STEP(2, acc2);
  P2STEP(3, acc2);

  // VN epilogue math (same VALU chain), folded to sink
  float fsum = 0.f;
  #pragma unroll
  for (int nt = 0; nt < 2; ++nt) {
    #pragma unroll
    for (int r = 0; r < 4; ++r) {
      float x0 = acc1[0][nt][r], x1 = acc1[1][nt][r], x2 = acc1[2][nt][r];
      float d0 = acc2[0][nt][r], d1 = acc2[1][nt][r], d2 = acc2[2][nt][r];
      float dot = x0 * d0 + x1 * d1 + x2 * d2;
      float dn = d0 * d0 + d1 * d1 + d2 * d2;
      float s = (dot < 0.0f) ? (0.8f * dot * __builtin_amdgcn_rcpf(dn + 1e-6f))
                             : 0.0f;
      fsum += (x0 - s * d0) + (x1 - s * d1) + (x2 - s * d2);
    }
  }
  union { float f; unsigned u; } cvt; cvt.f = fsum;
  sink[blockIdx.x * 512 + tid] = cvt.u;
}

extern "C" void kernel_launch(void* const* d_in, const int* in_sizes, int n_in,
                              void* d_out, int out_size, void* d_ws, size_t ws_size,
                              hipStream_t stream) {
  const float* X = (const float*)d_in[0];   // [8,4096,128,3]
  const float* J = (const float*)d_in[1];   // [8,4096,128,3,2]
  const float* A = (const float*)d_in[2];   // [256,128]
  const float* B = (const float*)d_in[3];   // [256,128]
  const float* C = (const float*)d_in[4];   // [256,128]
  const float* W = (const float*)d_in[5];   // [256,256]
  unsigned short* M3h = (unsigned short*)d_ws;          // 32768 u16
  unsigned short* M3m = M3h + 128 * 256;                // 32768 u16
  unsigned short* WMh = M3m + 128 * 256;                // 32768 u16
  unsigned short* WMm = WMh + 128 * 256;                // 32768 u16
  float* M3f = (float*)(WMm + 128 * 256);               // 32768 f32 -> 384 KB
  unsigned* sink = (unsigned*)(M3f + 128 * 256);        // 2048*512*4B = 4 MB
  float* out = (float*)d_out;               // [8,256,3,4096]

  prep1_kernel<<<128, 256, 0, stream>>>(A, B, C, M3f, M3h, M3m);
  prep2_kernel<<<256, 128, 0, stream>>>(W, M3f, WMh, WMm);
  affine_vnrelu_mfma<<<NBLK, 512, 0, stream>>>(
      X, J, M3h, M3m, WMh, WMm, out);
  // ---- ablation probes (write only to ws; dur_total - 280.7 = t1 + t2) ----
  probe_nomfma<<<NBLK, 512, 0, stream>>>(X, J, M3h, M3m, WMh, WMm, sink);
  probe_mfmaonly<<<NBLK, 512, 0, stream>>>(sink);
}

// Round 13
// 298.021 us; speedup vs baseline: 1.2008x; 1.2008x over previous
//
#include <hip/hip_runtime.h>

// B=8, N=4096, Din=128, Dout=256. TT=16 tokens/block -> M = 3*16 = 48 rows.
// bf16 2-way split (hi/mid) + 3 product-class MFMAs = ~24-bit GEMMs.
// R12 (resubmit — bench died in GPUAcquisitionTimeout; kernel never ran):
// INTERLEAVE G1/G2. R11 ablation: t1(no-MFMA) + t2(MFMA-only) ~= 77us,
// full kernel 122.5 -> phases compose nearly serially (~30us overlap only);
// also ~140us of bench dur_us is fixed graph/reset overhead. Pre-committed
// decision rule (t1 ~= t2) -> merge the two GEMMs into ONE per-ks loop:
//   - G1/G2 share the SAME aT fragments: LDS reads 48 -> 24 per wave;
//   - each ah/am feeds TWO independent 3-MFMA chains (acc1/acc2 alternating)
//     -> 2x independent MFMA streams, chain latency mutually hidden;
//   - weight loads for ks+1 hide under 2x compute; G1->G2 boundary gone.
// Math per accumulator identical -> absmax 0.5 unchanged.
// Also: prep2 2-way K-split + LDS reduce (serial chain 256->128, ~13->~7us);
// R11 probes removed (they cost 77us of score).
#define TT 16
#define NBLK 2048
#define LDA 136   // aT row stride (bf16): 128 + 8 pad

typedef short s16x8 __attribute__((ext_vector_type(8)));
typedef float f32x4 __attribute__((ext_vector_type(4)));

#define SCHED_FENCE() __builtin_amdgcn_sched_barrier(0)

__device__ __forceinline__ unsigned short f2bf(float f) {
  union { float f; unsigned u; } v; v.f = f;
  unsigned r = v.u + 0x7FFFu + ((v.u >> 16) & 1u);   // RNE; inputs finite
  return (unsigned short)(r >> 16);
}
__device__ __forceinline__ float bf2f(unsigned short h) {
  union { unsigned u; float f; } v; v.u = ((unsigned)h) << 16;
  return v.f;
}
__device__ __forceinline__ void split2(float x, unsigned short& h, unsigned short& m) {
  h = f2bf(x);
  m = f2bf(x - bf2f(h));   // exact subtraction
}

// prep1: M3 = A+B+C -> fp32 buffer (for prep2) + bf16x2 planes (for GEMM1)
__global__ __launch_bounds__(256) void prep1_kernel(
    const float* __restrict__ A, const float* __restrict__ Bm,
    const float* __restrict__ C,
    float* __restrict__ M3f,
    unsigned short* __restrict__ M3h, unsigned short* __restrict__ M3m) {
  int tid = blockIdx.x * 256 + threadIdx.x;   // 0..32767
  float s = A[tid] + Bm[tid] + C[tid];
  M3f[tid] = s;
  unsigned short h, m;
  split2(s, h, m);
  M3h[tid] = h; M3m[tid] = m;
}

// prep2: WM3[o][e] = sum_c W[o][c] * M3f[c][e], bf16x2 planes.
// R12: 256 threads/block, 2-way split over c (serial chain 256->128) + LDS
// combine. Deterministic (fixed summation order).
__global__ __launch_bounds__(256) void prep2_kernel(
    const float* __restrict__ W, const float* __restrict__ M3f,
    unsigned short* __restrict__ WMh, unsigned short* __restrict__ WMm) {
  __shared__ float wrow[256];
  __shared__ float part[128];
  const int o = blockIdx.x;
  const int t = threadIdx.x;        // 0..255
  const int e = t & 127;
  const int h = t >> 7;             // c-half 0/1
  wrow[t] = W[o * 256 + t];
  __syncthreads();
  float dot = 0.f;
  const int c0 = h * 128;
  #pragma unroll 8
  for (int c = c0; c < c0 + 128; ++c) dot += wrow[c] * M3f[c * 128 + e];
  if (h) part[e] = dot;
  __syncthreads();
  if (!h) {
    float d = dot + part[e];
    unsigned short hh, mm;
    split2(d, hh, mm);
    WMh[o * 128 + e] = hh; WMm[o * 128 + e] = mm;
  }
}

// rolling-prefetch load macros (all indices compile-time constant).
// Both weight planes are [256][128] u16; row = f0+nt*16+nl, col = ks*32+quad*8.
#define B1LOAD(ks) { \
  b1h[ks][0] = *(const s16x8*)(M3h + fB + (ks) * 32); \
  b1m[ks][0] = *(const s16x8*)(M3m + fB + (ks) * 32); \
  b1h[ks][1] = *(const s16x8*)(M3h + fB + 2048 + (ks) * 32); \
  b1m[ks][1] = *(const s16x8*)(M3m + fB + 2048 + (ks) * 32); }

#define WMLOAD(ks) { \
  wmh[ks][0] = *(const s16x8*)(WMh + fB + (ks) * 32); \
  wmm[ks][0] = *(const s16x8*)(WMm + fB + (ks) * 32); \
  wmh[ks][1] = *(const s16x8*)(WMh + fB + 2048 + (ks) * 32); \
  wmm[ks][1] = *(const s16x8*)(WMm + fB + 2048 + (ks) * 32); }

// Interleaved G1+G2 step: one aT fragment pair feeds both accumulator chains,
// MFMAs alternating acc1/acc2 (independent -> mutually latency-hiding).
#define GSTEP(ks) { \
  const int e0 = (ks) * 32 + quad * 8; \
  _Pragma("unroll") \
  for (int mt = 0; mt < 3; ++mt) { \
    s16x8 ah = *(const s16x8*)(aTh + (mt * 16 + nl) * LDA + e0); \
    s16x8 am = *(const s16x8*)(aTm + (mt * 16 + nl) * LDA + e0); \
    _Pragma("unroll") \
    for (int nt = 0; nt < 2; ++nt) { \
      f32x4 a1 = acc1[mt][nt]; \
      f32x4 a2 = acc2[mt][nt]; \
      a1 = __builtin_amdgcn_mfma_f32_16x16x32_bf16(ah, b1h[ks][nt], a1, 0, 0, 0); \
      a2 = __builtin_amdgcn_mfma_f32_16x16x32_bf16(ah, wmh[ks][nt], a2, 0, 0, 0); \
      a1 = __builtin_amdgcn_mfma_f32_16x16x32_bf16(ah, b1m[ks][nt], a1, 0, 0, 0); \
      a2 = __builtin_amdgcn_mfma_f32_16x16x32_bf16(ah, wmm[ks][nt], a2, 0, 0, 0); \
      a1 = __builtin_amdgcn_mfma_f32_16x16x32_bf16(am, b1h[ks][nt], a1, 0, 0, 0); \
      a2 = __builtin_amdgcn_mfma_f32_16x16x32_bf16(am, wmh[ks][nt], a2, 0, 0, 0); \
      acc1[mt][nt] = a1; acc2[mt][nt] = a2; \
    } \
  } }

__global__ __launch_bounds__(512, 4) void affine_vnrelu_mfma(
    const float* __restrict__ X, const float* __restrict__ J,
    const unsigned short* __restrict__ M3h, const unsigned short* __restrict__ M3m,
    const unsigned short* __restrict__ WMh, const unsigned short* __restrict__ WMm,
    float* __restrict__ out) {
  __shared__ unsigned short smem[2 * 48 * LDA];   // aT hi/mid, 26112 B
  unsigned short* aTh = smem;
  unsigned short* aTm = smem + 48 * LDA;

  const int tid = threadIdx.x;
  const int lane = tid & 63;
  const int w = tid >> 6;          // wave 0..7 -> f slice [32w, 32w+32)
  const int quad = lane >> 4;
  const int nl = lane & 15;
  const long g0 = (long)blockIdx.x * TT;
  const int b = (int)(g0 >> 12);   // N = 4096
  const int n0 = (int)(g0 & 4095);
  const int f0 = w * 32;
  const int fB = (f0 + nl) * 128 + quad * 8;
  const f32x4 zz = {0.f, 0.f, 0.f, 0.f};

  // ---- early issue: ks=0 tiles of BOTH weight matrices, pinned through
  // phase A (in flight under its VALU, drained by the barrier) --------------
  s16x8 b1h[4][2], b1m[4][2];
  s16x8 wmh[4][2], wmm[4][2];
  B1LOAD(0); WMLOAD(0);
  SCHED_FENCE();

  // ---------------- Phase A (vectorized): 1 thread = 4 channels of 1 token --
  {
    int t = tid >> 5;                 // token 0..15
    int dch0 = (tid & 31) * 4;        // channel group
    const float* Xp = X + ((g0 + t) * 128 + dch0) * 3;   // 48B, 16B-aligned
    const float* Jp = J + ((g0 + t) * 128 + dch0) * 6;   // 96B, 16B-aligned
    float xf[12], jf[24];
    #pragma unroll
    for (int q = 0; q < 3; ++q) *(float4*)(xf + 4 * q) = ((const float4*)Xp)[q];
    #pragma unroll
    for (int q = 0; q < 6; ++q) *(float4*)(jf + 4 * q) = ((const float4*)Jp)[q];

    unsigned short hs[3][4], ms[3][4];
    #pragma unroll
    for (int e = 0; e < 4; ++e) {
      float x0 = xf[3 * e], x1 = xf[3 * e + 1], x2 = xf[3 * e + 2];
      float j0 = jf[6 * e],     j1 = jf[6 * e + 1], j2 = jf[6 * e + 2];
      float j3 = jf[6 * e + 3], j4 = jf[6 * e + 4], j5 = jf[6 * e + 5];
      float c00 = j0, c01 = j2, c02 = j4;          // col0 of the 3x2
      float a20 = j1, a21 = j3, a22 = j5;          // col1
      // v_rsq on squared norm; fmaxf(nsq,1e-24) == reference max(n,1e-12)
      float nsq1 = c00 * c00 + c01 * c01 + c02 * c02;
      float inv1 = __builtin_amdgcn_rsqf(fmaxf(nsq1, 1e-24f));
      float b10 = c00 * inv1, b11 = c01 * inv1, b12 = c02 * inv1;
      float pr = b10 * a20 + b11 * a21 + b12 * a22;
      float u0 = a20 - pr * b10, u1 = a21 - pr * b11, u2 = a22 - pr * b12;
      float nsq2 = u0 * u0 + u1 * u1 + u2 * u2;
      float inv2 = __builtin_amdgcn_rsqf(fmaxf(nsq2, 1e-24f));
      float b20 = u0 * inv2, b21 = u1 * inv2, b22 = u2 * inv2;
      float b30 = b11 * b22 - b12 * b21;
      float b31 = b12 * b20 - b10 * b22;
      float b32 = b10 * b21 - b11 * b20;
      split2(b10 * x0 + b11 * x1 + b12 * x2, hs[0][e], ms[0][e]);
      split2(b20 * x0 + b21 * x1 + b22 * x2, hs[1][e], ms[1][e]);
      split2(b30 * x0 + b31 * x1 + b32 * x2, hs[2][e], ms[2][e]);
    }
    #pragma unroll
    for (int i = 0; i < 3; ++i) {
      short4 vh, vm;
      vh.x = hs[i][0]; vh.y = hs[i][1]; vh.z = hs[i][2]; vh.w = hs[i][3];
      vm.x = ms[i][0]; vm.y = ms[i][1]; vm.z = ms[i][2]; vm.w = ms[i][3];
      int ro = (i * 16 + t) * LDA + dch0;
      *(short4*)(aTh + ro) = vh;    // 8B-aligned (LDA even, dch0%4==0)
      *(short4*)(aTm + ro) = vm;
    }
  }
  __syncthreads();   // the single barrier: aT ready

  // ---------------- fused GEMM1+GEMM2 over ks (shared aT fragments) ---------
  f32x4 acc1[3][2], acc2[3][2];
  #pragma unroll
  for (int mt = 0; mt < 3; ++mt)
    #pragma unroll
    for (int nt = 0; nt < 2; ++nt) { acc1[mt][nt] = zz; acc2[mt][nt] = zz; }

  B1LOAD(1); WMLOAD(1);
  SCHED_FENCE();
  GSTEP(0);
  B1LOAD(2); WMLOAD(2);
  SCHED_FENCE();
  GSTEP(1);
  B1LOAD(3); WMLOAD(3);
  SCHED_FENCE();
  GSTEP(2);
  GSTEP(3);

  // ---------------- VN-LeakyReLU (lane-local, exact fp32 x) + stores --------
  // lane holds x_i = acc1[i][nt][r], d_i = acc2[i][nt][r] at the SAME (f, t):
  // f = f0 + nt*16 + nl, t = quad*4 + r.
  #pragma unroll
  for (int nt = 0; nt < 2; ++nt) {
    int f = f0 + nt * 16 + nl;
    float* ob = out + ((long)(b * 256 + f) * 3) * 4096 + n0 + quad * 4;
    float o[3][4];
    #pragma unroll
    for (int r = 0; r < 4; ++r) {
      float x0 = acc1[0][nt][r], x1 = acc1[1][nt][r], x2 = acc1[2][nt][r];
      float d0 = acc2[0][nt][r], d1 = acc2[1][nt][r], d2 = acc2[2][nt][r];
      float dot = x0 * d0 + x1 * d1 + x2 * d2;
      float dn = d0 * d0 + d1 * d1 + d2 * d2;
      float s = (dot < 0.0f) ? (0.8f * dot * __builtin_amdgcn_rcpf(dn + 1e-6f))
                             : 0.0f;
      o[0][r] = x0 - s * d0;
      o[1][r] = x1 - s * d1;
      o[2][r] = x2 - s * d2;
    }
    #pragma unroll
    for (int i = 0; i < 3; ++i)
      *(float4*)(ob + ((long)i * 4096)) = make_float4(o[i][0], o[i][1], o[i][2], o[i][3]);
  }
}

extern "C" void kernel_launch(void* const* d_in, const int* in_sizes, int n_in,
                              void* d_out, int out_size, void* d_ws, size_t ws_size,
                              hipStream_t stream) {
  const float* X = (const float*)d_in[0];   // [8,4096,128,3]
  const float* J = (const float*)d_in[1];   // [8,4096,128,3,2]
  const float* A = (const float*)d_in[2];   // [256,128]
  const float* B = (const float*)d_in[3];   // [256,128]
  const float* C = (const float*)d_in[4];   // [256,128]
  const float* W = (const float*)d_in[5];   // [256,256]
  unsigned short* M3h = (unsigned short*)d_ws;          // 32768 u16
  unsigned short* M3m = M3h + 128 * 256;                // 32768 u16
  unsigned short* WMh = M3m + 128 * 256;                // 32768 u16
  unsigned short* WMm = WMh + 128 * 256;                // 32768 u16
  float* M3f = (float*)(WMm + 128 * 256);               // 32768 f32; total 384KB
  float* out = (float*)d_out;               // [8,256,3,4096]

  prep1_kernel<<<128, 256, 0, stream>>>(A, B, C, M3f, M3h, M3m);
  prep2_kernel<<<256, 256, 0, stream>>>(W, M3f, WMh, WMm);
  affine_vnrelu_mfma<<<NBLK, 512, 0, stream>>>(
      X, J, M3h, M3m, WMh, WMm, out);
}